// Round 11
// baseline (308.859 us; speedup 1.0000x reference)
//
#include <hip/hip_runtime.h>
#include <math.h>

#define D 96
#define RSQ 0.10206207261596577f  // 1/sqrt(96)

typedef __attribute__((ext_vector_type(8))) short short8;
typedef __attribute__((ext_vector_type(4))) float f32x4;

__device__ __forceinline__ unsigned short f2bf(float f){
  unsigned u = __float_as_uint(f);
  unsigned r = (u + 0x7fff + ((u >> 16) & 1)) >> 16;  // RNE
  return (unsigned short)r;
}
__device__ __forceinline__ float bf2f(unsigned short h){
  return __uint_as_float(((unsigned)h) << 16);
}
__device__ __forceinline__ float bflo(unsigned u){ return __uint_as_float(u << 16); }
__device__ __forceinline__ float bfhi(unsigned u){ return __uint_as_float(u & 0xffff0000u); }
__device__ __forceinline__ int lbound(const int* __restrict__ a, int n, int v){
  int lo = 0, hi = n;
  while (lo < hi){ int mid = (lo + hi) >> 1; if (a[mid] < v) lo = mid + 1; else hi = mid; }
  return lo;
}

// K0: weight prep (transpose + hi/lo bf16 split) + degree histogram, keeping rank[e]
__global__ __launch_bounds__(256) void k_wprep_deg(
    const float* __restrict__ w1, const float* __restrict__ w2,
    const float* __restrict__ w3, const float* __restrict__ w4,
    unsigned short* __restrict__ wt_h, unsigned short* __restrict__ wt_l,
    const int* __restrict__ dstI, int* __restrict__ deg,
    int* __restrict__ rank, int E){
  int gtid = blockIdx.x * 256 + threadIdx.x;
  if (gtid < 4 * D * D){
    int m = gtid / (D * D);
    int r = gtid % (D * D);
    int nn = r / D, k = r % D;
    const float* w = (m == 0) ? w1 : (m == 1) ? w2 : (m == 2) ? w3 : w4;
    float v = w[k * D + nn];
    unsigned short h = f2bf(v);
    wt_h[gtid] = h;
    wt_l[gtid] = f2bf(v - bf2f(h));
  }
  if (gtid < E) rank[gtid] = atomicAdd(&deg[dstI[gtid]], 1);
}

// K1: weights-stationary persistent transform. 256 blocks (1/CU, LDS-forced), 4 waves.
// All 4 hi/lo weight matrices staged to LDS ONCE per block; grid-stride over 16-node
// tiles; steady-state loop touches only LDS + MFMA + stores (no global-load latency).
// Wave wv computes x@w_wv; wave 2 also computes fused p5 = dot(x3,w5), pb = dot(x3,b5).
__global__ __launch_bounds__(256) void k_transform_mfma(
    const float* __restrict__ x,
    const unsigned short* __restrict__ wt_h, const unsigned short* __restrict__ wt_l,
    const float* __restrict__ b1, const float* __restrict__ b2,
    const float* __restrict__ b3, const float* __restrict__ b4,
    const float* __restrict__ w5, const float* __restrict__ b5,
    float* __restrict__ acc_o, unsigned short* __restrict__ x24,
    float* __restrict__ x3o,
    float* __restrict__ p5, float* __restrict__ pb, int n, int NT){
  __shared__ __align__(16) unsigned short wlds[4][2][D * D];  // 147456 B
  __shared__ __align__(16) unsigned short xs_h[16][104];      // 3328 B
  __shared__ __align__(16) unsigned short xs_l[16][104];      // 3328 B
  int tid = threadIdx.x;

  // ---- stage all weights into LDS (once per block) ----
  {
    const short8* gh = (const short8*)wt_h;
    const short8* gl = (const short8*)wt_l;
    for (int c = tid; c < 4 * D * D / 8; c += 256){   // 4608 chunks
      int m = c / (D * D / 8);                        // 1152 chunks per matrix
      int r = c - m * (D * D / 8);
      *(short8*)&wlds[m][0][r * 8] = gh[c];
      *(short8*)&wlds[m][1][r * 8] = gl[c];
    }
  }

  int wv = tid >> 6;
  int lane = tid & 63, lr = lane & 15, kg = lane >> 4;
  const unsigned short* Wh = &wlds[wv][0][0];
  const unsigned short* Wl = &wlds[wv][1][0];
  const float* bias = (wv == 0) ? b1 : (wv == 1) ? b2 : (wv == 2) ? b3 : b4;

  for (int tile = blockIdx.x; tile < NT; tile += gridDim.x){
    int n0 = tile * 16;
    __syncthreads();   // xs free for overwrite (and weights ready on first iter)
    for (int e = tid; e < 16 * D; e += 256){
      int r = e / D, cc = e % D;
      int node = n0 + r;
      float v = (node < n) ? x[(size_t)node * D + cc] : 0.0f;
      unsigned short h = f2bf(v);
      xs_h[r][cc] = h;
      xs_l[r][cc] = f2bf(v - bf2f(h));
    }
    __syncthreads();

    f32x4 acc[6];
    #pragma unroll
    for (int i = 0; i < 6; ++i) acc[i] = (f32x4){0, 0, 0, 0};
    #pragma unroll
    for (int k0i = 0; k0i < 3; ++k0i){
      int kb = k0i * 32 + kg * 8;
      short8 ah = *(const short8*)&xs_h[lr][kb];
      short8 al = *(const short8*)&xs_l[lr][kb];
      #pragma unroll
      for (int nc = 0; nc < 6; ++nc){
        int col = nc * 16 + lr;
        short8 bh = *(const short8*)(Wh + col * D + kb);
        short8 bl = *(const short8*)(Wl + col * D + kb);
        acc[nc] = __builtin_amdgcn_mfma_f32_16x16x32_bf16(ah, bh, acc[nc], 0, 0, 0);
        acc[nc] = __builtin_amdgcn_mfma_f32_16x16x32_bf16(ah, bl, acc[nc], 0, 0, 0);
        acc[nc] = __builtin_amdgcn_mfma_f32_16x16x32_bf16(al, bh, acc[nc], 0, 0, 0);
      }
    }

    // epilogue: bias + scatter to outputs; wv2 accumulates p5/pb
    f32x4 p5a = {0, 0, 0, 0}, pba = {0, 0, 0, 0};
    #pragma unroll
    for (int nc = 0; nc < 6; ++nc){
      int col = nc * 16 + lr;
      float bb = bias[col];
      float w5v = w5[col], b5v = b5[col];
      #pragma unroll
      for (int q = 0; q < 4; ++q){
        float v = acc[nc][q] + bb;
        int row = kg * 4 + q;
        if (n0 + row < n){
          if (wv == 0) acc_o[(size_t)(n0 + row) * D + col] = v;
          else if (wv == 1) x24[(size_t)(n0 + row) * 192 + 96 + col] = f2bf(v);
          else if (wv == 2) x3o[(size_t)(n0 + row) * D + col] = v;
          else x24[(size_t)(n0 + row) * 192 + col] = f2bf(v);
        }
        p5a[q] += v * w5v;
        pba[q] += v * b5v;
      }
    }
    if (wv == 2){
      #pragma unroll
      for (int off = 1; off < 16; off <<= 1){
        #pragma unroll
        for (int q = 0; q < 4; ++q){
          p5a[q] += __shfl_xor(p5a[q], off);
          pba[q] += __shfl_xor(pba[q], off);
        }
      }
      if (lr == 0){
        #pragma unroll
        for (int q = 0; q < 4; ++q){
          int row = kg * 4 + q;
          if (n0 + row < n){ p5[n0 + row] = p5a[q]; pb[n0 + row] = pba[q]; }
        }
      }
    }
  }
}

// K3a: per-block exclusive scan (256 elements/block) + block totals
__global__ __launch_bounds__(256) void k_scanA(
    const int* __restrict__ deg, int* __restrict__ rowp,
    int* __restrict__ partials, int n){
  __shared__ int ws[4];
  int tid = threadIdx.x, lane = tid & 63, wid = tid >> 6;
  int i = blockIdx.x * 256 + tid;
  int v = (i < n) ? deg[i] : 0;
  int s = v;
  #pragma unroll
  for (int off = 1; off < 64; off <<= 1){ int u = __shfl_up(s, off); if (lane >= off) s += u; }
  if (lane == 63) ws[wid] = s;
  __syncthreads();
  if (tid < 4){
    int u = ws[tid];
    #pragma unroll
    for (int off = 1; off < 4; off <<= 1){ int q = __shfl_up(u, off); if (tid >= off) u += q; }
    ws[tid] = u;
  }
  __syncthreads();
  int woff = wid ? ws[wid - 1] : 0;
  if (i < n) rowp[i] = woff + s - v;   // block-local exclusive prefix
  if (tid == 255) partials[blockIdx.x] = ws[3];
}

// K3b: exclusive scan of block totals (in place) + grand total -> rowp[n]
__global__ __launch_bounds__(256) void k_scanB(
    int* __restrict__ partials, int* __restrict__ rowp, int nb, int n){
  __shared__ int ws[4];
  int tid = threadIdx.x, lane = tid & 63, wid = tid >> 6;
  int running = 0;
  for (int base = 0; base < nb; base += 256){
    int i = base + tid;
    int v = (i < nb) ? partials[i] : 0;
    int s = v;
    #pragma unroll
    for (int off = 1; off < 64; off <<= 1){ int u = __shfl_up(s, off); if (lane >= off) s += u; }
    if (lane == 63) ws[wid] = s;
    __syncthreads();
    if (tid < 4){
      int u = ws[tid];
      #pragma unroll
      for (int off = 1; off < 4; off <<= 1){ int q = __shfl_up(u, off); if (tid >= off) u += q; }
      ws[tid] = u;
    }
    __syncthreads();
    int woff = wid ? ws[wid - 1] : 0;
    if (i < nb) partials[i] = running + woff + s - v;
    running += ws[3];
    __syncthreads();
  }
  if (tid == 0) rowp[n] = running;
}

// K4: scatter (src, eattr) into CSR order — atomic-free via precomputed rank
__global__ __launch_bounds__(256) void k_scatter(
    const int* __restrict__ srcI, const int* __restrict__ dstI,
    const float* __restrict__ eattr, const int* __restrict__ rowp,
    const int* __restrict__ partials, const int* __restrict__ rank,
    int2* __restrict__ sortedSE, int E){
  int e = blockIdx.x * blockDim.x + threadIdx.x;
  if (e >= E) return;
  int t = dstI[e];
  int pos = rowp[t] + partials[t >> 8] + rank[e];
  sortedSE[pos] = make_int2(srcI[e], __float_as_int(eattr[e]));
}

// K5: fused attention per dst row — one wave per node, 16 lanes per edge,
// 8 edges in flight; interleaved x24 gathers (one 384B row per edge); online softmax.
__global__ __launch_bounds__(256) void k_attn(
    const unsigned short* __restrict__ x24, const float* __restrict__ x3,
    const float* __restrict__ p5,
    const float* __restrict__ pb, const int2* __restrict__ sortedSE,
    const int* __restrict__ rowp, const int* __restrict__ partials,
    float* __restrict__ node_acc, int n){
  int t = blockIdx.x * 4 + (threadIdx.x >> 6);
  int lane = threadIdx.x & 63;
  if (t >= n) return;
  int beg = rowp[t] + partials[t >> 8];
  int end = (t + 1 < n) ? (rowp[t + 1] + partials[(t + 1) >> 8]) : rowp[n];
  if (beg == end) return;
  int j = lane & 15;
  int g = lane >> 4;

  const float2* r3 = (const float2*)(x3 + (size_t)t * D);
  float2 v0 = r3[j], v1 = r3[j + 16], v2 = r3[j + 32];
  float p5t = p5[t], pbt = pb[t];

  float m = -INFINITY, dsum = 0.0f;
  float a0 = 0, a1 = 0, a2 = 0, a3 = 0, a4 = 0, a5 = 0;

  for (int c = beg; c < end; c += 8){
    int eA = c + g, eB = c + 4 + g;
    bool actA = eA < end, actB = eB < end;
    int2 seA = sortedSE[actA ? eA : end - 1];
    int2 seB = sortedSE[actB ? eB : end - 1];
    const unsigned* rA = (const unsigned*)(x24 + (size_t)seA.x * 192);
    const unsigned* rB = (const unsigned*)(x24 + (size_t)seB.x * 192);
    unsigned uA0 = rA[j], uA1 = rA[j + 16], uA2 = rA[j + 32];
    unsigned uB0 = rB[j], uB1 = rB[j + 16], uB2 = rB[j + 32];
    float sA = v0.x * bflo(uA0) + v0.y * bfhi(uA0)
             + v1.x * bflo(uA1) + v1.y * bfhi(uA1)
             + v2.x * bflo(uA2) + v2.y * bfhi(uA2);
    float sB = v0.x * bflo(uB0) + v0.y * bfhi(uB0)
             + v1.x * bflo(uB1) + v1.y * bfhi(uB1)
             + v2.x * bflo(uB2) + v2.y * bfhi(uB2);
    sA += __shfl_xor(sA, 1); sA += __shfl_xor(sA, 2);
    sA += __shfl_xor(sA, 4); sA += __shfl_xor(sA, 8);
    sB += __shfl_xor(sB, 1); sB += __shfl_xor(sB, 2);
    sB += __shfl_xor(sB, 4); sB += __shfl_xor(sB, 8);
    float scA = actA ? (sA + __int_as_float(seA.y) * p5t + pbt) * RSQ : -INFINITY;
    float scB = actB ? (sB + __int_as_float(seB.y) * p5t + pbt) * RSQ : -INFINITY;
    float mc = fmaxf(scA, scB);
    mc = fmaxf(mc, __shfl_xor(mc, 16));
    mc = fmaxf(mc, __shfl_xor(mc, 32));
    if (mc > m){
      float r = __expf(m - mc);   // 0 on first iteration (m = -inf)
      dsum *= r; a0 *= r; a1 *= r; a2 *= r; a3 *= r; a4 *= r; a5 *= r;
      m = mc;
    }
    float wA = __expf(scA - m);   // 0 for inactive
    float wB = __expf(scB - m);
    dsum += wA + wB;
    unsigned qA0 = rA[48 + j], qA1 = rA[48 + j + 16], qA2 = rA[48 + j + 32];
    unsigned qB0 = rB[48 + j], qB1 = rB[48 + j + 16], qB2 = rB[48 + j + 32];
    a0 += wA * bflo(qA0) + wB * bflo(qB0);
    a1 += wA * bfhi(qA0) + wB * bfhi(qB0);
    a2 += wA * bflo(qA1) + wB * bflo(qB1);
    a3 += wA * bfhi(qA1) + wB * bfhi(qB1);
    a4 += wA * bflo(qA2) + wB * bflo(qB2);
    a5 += wA * bfhi(qA2) + wB * bfhi(qB2);
  }
  a0 += __shfl_xor(a0, 16); a0 += __shfl_xor(a0, 32);
  a1 += __shfl_xor(a1, 16); a1 += __shfl_xor(a1, 32);
  a2 += __shfl_xor(a2, 16); a2 += __shfl_xor(a2, 32);
  a3 += __shfl_xor(a3, 16); a3 += __shfl_xor(a3, 32);
  a4 += __shfl_xor(a4, 16); a4 += __shfl_xor(a4, 32);
  a5 += __shfl_xor(a5, 16); a5 += __shfl_xor(a5, 32);
  dsum += __shfl_xor(dsum, 16); dsum += __shfl_xor(dsum, 32);
  float inv = 1.0f / (dsum + 1e-16f);
  if (lane < 16){
    size_t o = (size_t)t * D + 2 * j;   // elems 2j,2j+1 / +32 / +64
    node_acc[o]      += a0 * inv;
    node_acc[o + 1]  += a1 * inv;
    node_acc[o + 32] += a2 * inv;
    node_acc[o + 33] += a3 * inv;
    node_acc[o + 64] += a4 * inv;
    node_acc[o + 65] += a5 * inv;
  }
}

// K6: per-graph partial sums (batch sorted; binary-search boundaries). No fence.
__global__ __launch_bounds__(96) void k_pool(
    const float* __restrict__ node_out, const int* __restrict__ batch,
    float* __restrict__ sums, int n){
  int g = blockIdx.x;
  int chunk = blockIdx.y, nch = gridDim.y;
  int lo = lbound(batch, n, g);
  int hi = lbound(batch, n, g + 1);
  int cnt = hi - lo;
  if (cnt <= 0) return;
  int per = (cnt + nch - 1) / nch;
  int b = lo + chunk * per;
  int e = min(b + per, hi);
  if (b >= e) return;
  int d = threadIdx.x;
  float s = 0.0f;
  for (int r = b; r < e; ++r) s += node_out[(size_t)r * D + d];
  atomicAdd(&sums[g * D + d], s);
}

// K7: divide by counts
__global__ __launch_bounds__(256) void k_final(
    const float* __restrict__ sums, const int* __restrict__ batch,
    float* __restrict__ out, int n, int total){
  int i = blockIdx.x * blockDim.x + threadIdx.x;
  if (i >= total) return;
  int g = i / D;
  int lo = lbound(batch, n, g);
  int hi = lbound(batch, n, g + 1);
  float c = (float)((hi - lo) > 1 ? (hi - lo) : 1);
  out[i] = sums[i] / c;
}

extern "C" void kernel_launch(void* const* d_in, const int* in_sizes, int n_in,
                              void* d_out, int out_size, void* d_ws, size_t ws_size,
                              hipStream_t stream){
  const float* x     = (const float*)d_in[0];
  const int*   eidx  = (const int*)d_in[1];
  const float* eattr = (const float*)d_in[2];
  const int*   batch = (const int*)d_in[3];
  const float* w1 = (const float*)d_in[4];
  const float* b1 = (const float*)d_in[5];
  const float* w2 = (const float*)d_in[6];
  const float* b2 = (const float*)d_in[7];
  const float* w3 = (const float*)d_in[8];
  const float* b3 = (const float*)d_in[9];
  const float* w4 = (const float*)d_in[10];
  const float* b4 = (const float*)d_in[11];
  const float* w5 = (const float*)d_in[12];
  const float* b5 = (const float*)d_in[13];
  float* out = (float*)d_out;

  const int N = in_sizes[0] / D;
  const int E = in_sizes[2];
  const int* srcI = eidx;
  const int* dstI = eidx + E;
  const int NB = (N + 255) / 256;
  const int NT = (N + 15) / 16;
  const int TGRID = (NT < 256) ? NT : 256;

  char* base = (char*)d_ws;
  size_t off = 0;
  auto alloc = [&](size_t bytes) -> char* {
    char* p = base + off;
    off = (off + bytes + 255) & ~(size_t)255;
    return p;
  };
  char* zbase = base;
  int*   deg   = (int*)alloc((size_t)N * 4);
  float* sums  = (float*)alloc((size_t)out_size * 4);
  size_t zbytes = off;
  float* node_acc = (float*)alloc((size_t)N * D * 4);
  unsigned short* x24 = (unsigned short*)alloc((size_t)N * 192 * 2);
  float* x3v      = (float*)alloc((size_t)N * D * 4);
  float* p5       = (float*)alloc((size_t)N * 4);
  float* pb       = (float*)alloc((size_t)N * 4);
  int*   rowp     = (int*)alloc((size_t)(N + 1) * 4);
  int*   partials = (int*)alloc((size_t)(NB + 1) * 4);
  int*   rank     = (int*)alloc((size_t)E * 4);
  int2*  sortedSE = (int2*)alloc((size_t)E * 8);
  unsigned short* wt_h = (unsigned short*)alloc((size_t)4 * D * D * 2);
  unsigned short* wt_l = (unsigned short*)alloc((size_t)4 * D * D * 2);
  (void)ws_size; (void)n_in;

  hipMemsetAsync(zbase, 0, zbytes, stream);

  k_wprep_deg<<<dim3((E + 255) / 256), dim3(256), 0, stream>>>(
      w1, w2, w3, w4, wt_h, wt_l, dstI, deg, rank, E);
  k_transform_mfma<<<dim3(TGRID), dim3(256), 0, stream>>>(
      x, wt_h, wt_l, b1, b2, b3, b4, w5, b5,
      node_acc, x24, x3v, p5, pb, N, NT);
  k_scanA<<<dim3(NB), dim3(256), 0, stream>>>(deg, rowp, partials, N);
  k_scanB<<<dim3(1), dim3(256), 0, stream>>>(partials, rowp, NB, N);
  k_scatter<<<dim3((E + 255) / 256), dim3(256), 0, stream>>>(
      srcI, dstI, eattr, rowp, partials, rank, sortedSE, E);
  k_attn<<<dim3((N + 3) / 4), dim3(256), 0, stream>>>(
      x24, x3v, p5, pb, sortedSE, rowp, partials, node_acc, N);
  k_pool<<<dim3(out_size / D, 32), dim3(D), 0, stream>>>(node_acc, batch, sums, N);
  k_final<<<dim3((out_size + 255) / 256), dim3(256), 0, stream>>>(
      sums, batch, out, N, out_size);
}

// Round 12
// 267.718 us; speedup vs baseline: 1.1537x; 1.1537x over previous
//
#include <hip/hip_runtime.h>
#include <math.h>

#define D 96
#define RSQ 0.10206207261596577f  // 1/sqrt(96)

typedef __attribute__((ext_vector_type(8))) short short8;
typedef __attribute__((ext_vector_type(4))) float f32x4;

__device__ __forceinline__ unsigned short f2bf(float f){
  unsigned u = __float_as_uint(f);
  unsigned r = (u + 0x7fff + ((u >> 16) & 1)) >> 16;  // RNE
  return (unsigned short)r;
}
__device__ __forceinline__ float bf2f(unsigned short h){
  return __uint_as_float(((unsigned)h) << 16);
}
__device__ __forceinline__ float bflo(unsigned u){ return __uint_as_float(u << 16); }
__device__ __forceinline__ float bfhi(unsigned u){ return __uint_as_float(u & 0xffff0000u); }
__device__ __forceinline__ int lbound(const int* __restrict__ a, int n, int v){
  int lo = 0, hi = n;
  while (lo < hi){ int mid = (lo + hi) >> 1; if (a[mid] < v) lo = mid + 1; else hi = mid; }
  return lo;
}

// K0: weight prep (transpose + hi/lo bf16 split) + degree histogram, keeping rank[e]
__global__ __launch_bounds__(256) void k_wprep_deg(
    const float* __restrict__ w1, const float* __restrict__ w2,
    const float* __restrict__ w3, const float* __restrict__ w4,
    unsigned short* __restrict__ wt_h, unsigned short* __restrict__ wt_l,
    const int* __restrict__ dstI, int* __restrict__ deg,
    int* __restrict__ rank, int E){
  int gtid = blockIdx.x * 256 + threadIdx.x;
  if (gtid < 4 * D * D){
    int m = gtid / (D * D);
    int r = gtid % (D * D);
    int nn = r / D, k = r % D;
    const float* w = (m == 0) ? w1 : (m == 1) ? w2 : (m == 2) ? w3 : w4;
    float v = w[k * D + nn];
    unsigned short h = f2bf(v);
    wt_h[gtid] = h;
    wt_l[gtid] = f2bf(v - bf2f(h));
  }
  if (gtid < E) rank[gtid] = atomicAdd(&deg[dstI[gtid]], 1);
}

// K1: node transforms via split-bf16 MFMA. Block = 16 nodes, 4 waves; wave wv
// computes x@w_wv. Per k-step: ALL 12 B fragments loaded into named registers
// BEFORE the 18 MFMAs (12-deep memory-level parallelism on the L2 B-loads —
// the R9 version reused 2 regs and serialized 36 ~250cy round trips).
// x2/x4 written bf16-interleaved into x24; acc/x3 f32; wave 2 computes p5/pb.
__global__ __launch_bounds__(256) void k_transform_mfma(
    const float* __restrict__ x,
    const unsigned short* __restrict__ wt_h, const unsigned short* __restrict__ wt_l,
    const float* __restrict__ b1, const float* __restrict__ b2,
    const float* __restrict__ b3, const float* __restrict__ b4,
    const float* __restrict__ w5, const float* __restrict__ b5,
    float* __restrict__ acc_o, unsigned short* __restrict__ x24,
    float* __restrict__ x3o,
    float* __restrict__ p5, float* __restrict__ pb, int n){
  __shared__ __align__(16) unsigned short xs_h[16][104];
  __shared__ __align__(16) unsigned short xs_l[16][104];
  int tid = threadIdx.x;
  int n0 = blockIdx.x * 16;
  for (int e = tid; e < 16 * D; e += 256){
    int r = e / D, c = e % D;
    int node = n0 + r;
    float v = (node < n) ? x[(size_t)node * D + c] : 0.0f;
    unsigned short h = f2bf(v);
    xs_h[r][c] = h;
    xs_l[r][c] = f2bf(v - bf2f(h));
  }
  __syncthreads();

  int wv = tid >> 6;
  int lane = tid & 63, lr = lane & 15, kg = lane >> 4;
  const unsigned short* Wh = wt_h + (size_t)wv * D * D;
  const unsigned short* Wl = wt_l + (size_t)wv * D * D;

  f32x4 acc0 = {0,0,0,0}, acc1 = {0,0,0,0}, acc2 = {0,0,0,0};
  f32x4 acc3 = {0,0,0,0}, acc4 = {0,0,0,0}, acc5 = {0,0,0,0};

  #pragma unroll
  for (int k0i = 0; k0i < 3; ++k0i){
    int kb = k0i * 32 + kg * 8;
    short8 ah = *(const short8*)&xs_h[lr][kb];
    short8 al = *(const short8*)&xs_l[lr][kb];
    const unsigned short* bp = Wh + lr * D + kb;
    const unsigned short* lp = Wl + lr * D + kb;
    // 12 independent L2 loads, all issued before any consumer
    short8 bh0 = *(const short8*)(bp);
    short8 bh1 = *(const short8*)(bp + 16 * D);
    short8 bh2 = *(const short8*)(bp + 32 * D);
    short8 bh3 = *(const short8*)(bp + 48 * D);
    short8 bh4 = *(const short8*)(bp + 64 * D);
    short8 bh5 = *(const short8*)(bp + 80 * D);
    short8 bl0 = *(const short8*)(lp);
    short8 bl1 = *(const short8*)(lp + 16 * D);
    short8 bl2 = *(const short8*)(lp + 32 * D);
    short8 bl3 = *(const short8*)(lp + 48 * D);
    short8 bl4 = *(const short8*)(lp + 64 * D);
    short8 bl5 = *(const short8*)(lp + 80 * D);
    acc0 = __builtin_amdgcn_mfma_f32_16x16x32_bf16(ah, bh0, acc0, 0, 0, 0);
    acc0 = __builtin_amdgcn_mfma_f32_16x16x32_bf16(ah, bl0, acc0, 0, 0, 0);
    acc0 = __builtin_amdgcn_mfma_f32_16x16x32_bf16(al, bh0, acc0, 0, 0, 0);
    acc1 = __builtin_amdgcn_mfma_f32_16x16x32_bf16(ah, bh1, acc1, 0, 0, 0);
    acc1 = __builtin_amdgcn_mfma_f32_16x16x32_bf16(ah, bl1, acc1, 0, 0, 0);
    acc1 = __builtin_amdgcn_mfma_f32_16x16x32_bf16(al, bh1, acc1, 0, 0, 0);
    acc2 = __builtin_amdgcn_mfma_f32_16x16x32_bf16(ah, bh2, acc2, 0, 0, 0);
    acc2 = __builtin_amdgcn_mfma_f32_16x16x32_bf16(ah, bl2, acc2, 0, 0, 0);
    acc2 = __builtin_amdgcn_mfma_f32_16x16x32_bf16(al, bh2, acc2, 0, 0, 0);
    acc3 = __builtin_amdgcn_mfma_f32_16x16x32_bf16(ah, bh3, acc3, 0, 0, 0);
    acc3 = __builtin_amdgcn_mfma_f32_16x16x32_bf16(ah, bl3, acc3, 0, 0, 0);
    acc3 = __builtin_amdgcn_mfma_f32_16x16x32_bf16(al, bh3, acc3, 0, 0, 0);
    acc4 = __builtin_amdgcn_mfma_f32_16x16x32_bf16(ah, bh4, acc4, 0, 0, 0);
    acc4 = __builtin_amdgcn_mfma_f32_16x16x32_bf16(ah, bl4, acc4, 0, 0, 0);
    acc4 = __builtin_amdgcn_mfma_f32_16x16x32_bf16(al, bh4, acc4, 0, 0, 0);
    acc5 = __builtin_amdgcn_mfma_f32_16x16x32_bf16(ah, bh5, acc5, 0, 0, 0);
    acc5 = __builtin_amdgcn_mfma_f32_16x16x32_bf16(ah, bl5, acc5, 0, 0, 0);
    acc5 = __builtin_amdgcn_mfma_f32_16x16x32_bf16(al, bh5, acc5, 0, 0, 0);
  }

  const float* bias = (wv == 0) ? b1 : (wv == 1) ? b2 : (wv == 2) ? b3 : b4;
  f32x4 p5a = {0, 0, 0, 0}, pba = {0, 0, 0, 0};
  #define EPI_BODY(nc, C) { \
    int col = (nc) * 16 + lr; \
    float bb = bias[col]; \
    float w5v = w5[col], b5v = b5[col]; \
    _Pragma("unroll") \
    for (int q = 0; q < 4; ++q){ \
      float v = C[q] + bb; \
      int row = kg * 4 + q; \
      if (n0 + row < n){ \
        if (wv == 0) acc_o[(size_t)(n0 + row) * D + col] = v; \
        else if (wv == 1) x24[(size_t)(n0 + row) * 192 + 96 + col] = f2bf(v); \
        else if (wv == 2) x3o[(size_t)(n0 + row) * D + col] = v; \
        else x24[(size_t)(n0 + row) * 192 + col] = f2bf(v); \
      } \
      p5a[q] += v * w5v; \
      pba[q] += v * b5v; \
    } }
  EPI_BODY(0, acc0) EPI_BODY(1, acc1) EPI_BODY(2, acc2)
  EPI_BODY(3, acc3) EPI_BODY(4, acc4) EPI_BODY(5, acc5)
  #undef EPI_BODY

  if (wv == 2){
    #pragma unroll
    for (int off = 1; off < 16; off <<= 1){
      #pragma unroll
      for (int q = 0; q < 4; ++q){
        p5a[q] += __shfl_xor(p5a[q], off);
        pba[q] += __shfl_xor(pba[q], off);
      }
    }
    if (lr == 0){
      #pragma unroll
      for (int q = 0; q < 4; ++q){
        int row = kg * 4 + q;
        if (n0 + row < n){ p5[n0 + row] = p5a[q]; pb[n0 + row] = pba[q]; }
      }
    }
  }
}

// K3a: per-block exclusive scan (256 elements/block) + block totals
__global__ __launch_bounds__(256) void k_scanA(
    const int* __restrict__ deg, int* __restrict__ rowp,
    int* __restrict__ partials, int n){
  __shared__ int ws[4];
  int tid = threadIdx.x, lane = tid & 63, wid = tid >> 6;
  int i = blockIdx.x * 256 + tid;
  int v = (i < n) ? deg[i] : 0;
  int s = v;
  #pragma unroll
  for (int off = 1; off < 64; off <<= 1){ int u = __shfl_up(s, off); if (lane >= off) s += u; }
  if (lane == 63) ws[wid] = s;
  __syncthreads();
  if (tid < 4){
    int u = ws[tid];
    #pragma unroll
    for (int off = 1; off < 4; off <<= 1){ int q = __shfl_up(u, off); if (tid >= off) u += q; }
    ws[tid] = u;
  }
  __syncthreads();
  int woff = wid ? ws[wid - 1] : 0;
  if (i < n) rowp[i] = woff + s - v;   // block-local exclusive prefix
  if (tid == 255) partials[blockIdx.x] = ws[3];
}

// K3b: exclusive scan of block totals (in place) + grand total -> rowp[n]
__global__ __launch_bounds__(256) void k_scanB(
    int* __restrict__ partials, int* __restrict__ rowp, int nb, int n){
  __shared__ int ws[4];
  int tid = threadIdx.x, lane = tid & 63, wid = tid >> 6;
  int running = 0;
  for (int base = 0; base < nb; base += 256){
    int i = base + tid;
    int v = (i < nb) ? partials[i] : 0;
    int s = v;
    #pragma unroll
    for (int off = 1; off < 64; off <<= 1){ int u = __shfl_up(s, off); if (lane >= off) s += u; }
    if (lane == 63) ws[wid] = s;
    __syncthreads();
    if (tid < 4){
      int u = ws[tid];
      #pragma unroll
      for (int off = 1; off < 4; off <<= 1){ int q = __shfl_up(u, off); if (tid >= off) u += q; }
      ws[tid] = u;
    }
    __syncthreads();
    int woff = wid ? ws[wid - 1] : 0;
    if (i < nb) partials[i] = running + woff + s - v;
    running += ws[3];
    __syncthreads();
  }
  if (tid == 0) rowp[n] = running;
}

// K4: scatter (src, eattr) into CSR order — atomic-free via precomputed rank
__global__ __launch_bounds__(256) void k_scatter(
    const int* __restrict__ srcI, const int* __restrict__ dstI,
    const float* __restrict__ eattr, const int* __restrict__ rowp,
    const int* __restrict__ partials, const int* __restrict__ rank,
    int2* __restrict__ sortedSE, int E){
  int e = blockIdx.x * blockDim.x + threadIdx.x;
  if (e >= E) return;
  int t = dstI[e];
  int pos = rowp[t] + partials[t >> 8] + rank[e];
  sortedSE[pos] = make_int2(srcI[e], __float_as_int(eattr[e]));
}

// K5: fused attention per dst row — one wave per node, 16 lanes per edge,
// 8 edges in flight; interleaved x24 gathers (one 384B row per edge); online softmax.
__global__ __launch_bounds__(256) void k_attn(
    const unsigned short* __restrict__ x24, const float* __restrict__ x3,
    const float* __restrict__ p5,
    const float* __restrict__ pb, const int2* __restrict__ sortedSE,
    const int* __restrict__ rowp, const int* __restrict__ partials,
    float* __restrict__ node_acc, int n){
  int t = blockIdx.x * 4 + (threadIdx.x >> 6);
  int lane = threadIdx.x & 63;
  if (t >= n) return;
  int beg = rowp[t] + partials[t >> 8];
  int end = (t + 1 < n) ? (rowp[t + 1] + partials[(t + 1) >> 8]) : rowp[n];
  if (beg == end) return;
  int j = lane & 15;
  int g = lane >> 4;

  const float2* r3 = (const float2*)(x3 + (size_t)t * D);
  float2 v0 = r3[j], v1 = r3[j + 16], v2 = r3[j + 32];
  float p5t = p5[t], pbt = pb[t];

  float m = -INFINITY, dsum = 0.0f;
  float a0 = 0, a1 = 0, a2 = 0, a3 = 0, a4 = 0, a5 = 0;

  for (int c = beg; c < end; c += 8){
    int eA = c + g, eB = c + 4 + g;
    bool actA = eA < end, actB = eB < end;
    int2 seA = sortedSE[actA ? eA : end - 1];
    int2 seB = sortedSE[actB ? eB : end - 1];
    const unsigned* rA = (const unsigned*)(x24 + (size_t)seA.x * 192);
    const unsigned* rB = (const unsigned*)(x24 + (size_t)seB.x * 192);
    unsigned uA0 = rA[j], uA1 = rA[j + 16], uA2 = rA[j + 32];
    unsigned uB0 = rB[j], uB1 = rB[j + 16], uB2 = rB[j + 32];
    float sA = v0.x * bflo(uA0) + v0.y * bfhi(uA0)
             + v1.x * bflo(uA1) + v1.y * bfhi(uA1)
             + v2.x * bflo(uA2) + v2.y * bfhi(uA2);
    float sB = v0.x * bflo(uB0) + v0.y * bfhi(uB0)
             + v1.x * bflo(uB1) + v1.y * bfhi(uB1)
             + v2.x * bflo(uB2) + v2.y * bfhi(uB2);
    sA += __shfl_xor(sA, 1); sA += __shfl_xor(sA, 2);
    sA += __shfl_xor(sA, 4); sA += __shfl_xor(sA, 8);
    sB += __shfl_xor(sB, 1); sB += __shfl_xor(sB, 2);
    sB += __shfl_xor(sB, 4); sB += __shfl_xor(sB, 8);
    float scA = actA ? (sA + __int_as_float(seA.y) * p5t + pbt) * RSQ : -INFINITY;
    float scB = actB ? (sB + __int_as_float(seB.y) * p5t + pbt) * RSQ : -INFINITY;
    float mc = fmaxf(scA, scB);
    mc = fmaxf(mc, __shfl_xor(mc, 16));
    mc = fmaxf(mc, __shfl_xor(mc, 32));
    if (mc > m){
      float r = __expf(m - mc);   // 0 on first iteration (m = -inf)
      dsum *= r; a0 *= r; a1 *= r; a2 *= r; a3 *= r; a4 *= r; a5 *= r;
      m = mc;
    }
    float wA = __expf(scA - m);   // 0 for inactive
    float wB = __expf(scB - m);
    dsum += wA + wB;
    unsigned qA0 = rA[48 + j], qA1 = rA[48 + j + 16], qA2 = rA[48 + j + 32];
    unsigned qB0 = rB[48 + j], qB1 = rB[48 + j + 16], qB2 = rB[48 + j + 32];
    a0 += wA * bflo(qA0) + wB * bflo(qB0);
    a1 += wA * bfhi(qA0) + wB * bfhi(qB0);
    a2 += wA * bflo(qA1) + wB * bflo(qB1);
    a3 += wA * bfhi(qA1) + wB * bfhi(qB1);
    a4 += wA * bflo(qA2) + wB * bflo(qB2);
    a5 += wA * bfhi(qA2) + wB * bfhi(qB2);
  }
  a0 += __shfl_xor(a0, 16); a0 += __shfl_xor(a0, 32);
  a1 += __shfl_xor(a1, 16); a1 += __shfl_xor(a1, 32);
  a2 += __shfl_xor(a2, 16); a2 += __shfl_xor(a2, 32);
  a3 += __shfl_xor(a3, 16); a3 += __shfl_xor(a3, 32);
  a4 += __shfl_xor(a4, 16); a4 += __shfl_xor(a4, 32);
  a5 += __shfl_xor(a5, 16); a5 += __shfl_xor(a5, 32);
  dsum += __shfl_xor(dsum, 16); dsum += __shfl_xor(dsum, 32);
  float inv = 1.0f / (dsum + 1e-16f);
  if (lane < 16){
    size_t o = (size_t)t * D + 2 * j;   // elems 2j,2j+1 / +32 / +64
    node_acc[o]      += a0 * inv;
    node_acc[o + 1]  += a1 * inv;
    node_acc[o + 32] += a2 * inv;
    node_acc[o + 33] += a3 * inv;
    node_acc[o + 64] += a4 * inv;
    node_acc[o + 65] += a5 * inv;
  }
}

// K6: per-graph partial sums (batch sorted; binary-search boundaries). No fence.
__global__ __launch_bounds__(96) void k_pool(
    const float* __restrict__ node_out, const int* __restrict__ batch,
    float* __restrict__ sums, int n){
  int g = blockIdx.x;
  int chunk = blockIdx.y, nch = gridDim.y;
  int lo = lbound(batch, n, g);
  int hi = lbound(batch, n, g + 1);
  int cnt = hi - lo;
  if (cnt <= 0) return;
  int per = (cnt + nch - 1) / nch;
  int b = lo + chunk * per;
  int e = min(b + per, hi);
  if (b >= e) return;
  int d = threadIdx.x;
  float s = 0.0f;
  for (int r = b; r < e; ++r) s += node_out[(size_t)r * D + d];
  atomicAdd(&sums[g * D + d], s);
}

// K7: divide by counts
__global__ __launch_bounds__(256) void k_final(
    const float* __restrict__ sums, const int* __restrict__ batch,
    float* __restrict__ out, int n, int total){
  int i = blockIdx.x * blockDim.x + threadIdx.x;
  if (i >= total) return;
  int g = i / D;
  int lo = lbound(batch, n, g);
  int hi = lbound(batch, n, g + 1);
  float c = (float)((hi - lo) > 1 ? (hi - lo) : 1);
  out[i] = sums[i] / c;
}

extern "C" void kernel_launch(void* const* d_in, const int* in_sizes, int n_in,
                              void* d_out, int out_size, void* d_ws, size_t ws_size,
                              hipStream_t stream){
  const float* x     = (const float*)d_in[0];
  const int*   eidx  = (const int*)d_in[1];
  const float* eattr = (const float*)d_in[2];
  const int*   batch = (const int*)d_in[3];
  const float* w1 = (const float*)d_in[4];
  const float* b1 = (const float*)d_in[5];
  const float* w2 = (const float*)d_in[6];
  const float* b2 = (const float*)d_in[7];
  const float* w3 = (const float*)d_in[8];
  const float* b3 = (const float*)d_in[9];
  const float* w4 = (const float*)d_in[10];
  const float* b4 = (const float*)d_in[11];
  const float* w5 = (const float*)d_in[12];
  const float* b5 = (const float*)d_in[13];
  float* out = (float*)d_out;

  const int N = in_sizes[0] / D;
  const int E = in_sizes[2];
  const int* srcI = eidx;
  const int* dstI = eidx + E;
  const int NB = (N + 255) / 256;
  const int NT = (N + 15) / 16;

  char* base = (char*)d_ws;
  size_t off = 0;
  auto alloc = [&](size_t bytes) -> char* {
    char* p = base + off;
    off = (off + bytes + 255) & ~(size_t)255;
    return p;
  };
  char* zbase = base;
  int*   deg   = (int*)alloc((size_t)N * 4);
  float* sums  = (float*)alloc((size_t)out_size * 4);
  size_t zbytes = off;
  float* node_acc = (float*)alloc((size_t)N * D * 4);
  unsigned short* x24 = (unsigned short*)alloc((size_t)N * 192 * 2);
  float* x3v      = (float*)alloc((size_t)N * D * 4);
  float* p5       = (float*)alloc((size_t)N * 4);
  float* pb       = (float*)alloc((size_t)N * 4);
  int*   rowp     = (int*)alloc((size_t)(N + 1) * 4);
  int*   partials = (int*)alloc((size_t)(NB + 1) * 4);
  int*   rank     = (int*)alloc((size_t)E * 4);
  int2*  sortedSE = (int2*)alloc((size_t)E * 8);
  unsigned short* wt_h = (unsigned short*)alloc((size_t)4 * D * D * 2);
  unsigned short* wt_l = (unsigned short*)alloc((size_t)4 * D * D * 2);
  (void)ws_size; (void)n_in;

  hipMemsetAsync(zbase, 0, zbytes, stream);

  k_wprep_deg<<<dim3((E + 255) / 256), dim3(256), 0, stream>>>(
      w1, w2, w3, w4, wt_h, wt_l, dstI, deg, rank, E);
  k_transform_mfma<<<dim3(NT), dim3(256), 0, stream>>>(
      x, wt_h, wt_l, b1, b2, b3, b4, w5, b5,
      node_acc, x24, x3v, p5, pb, N);
  k_scanA<<<dim3(NB), dim3(256), 0, stream>>>(deg, rowp, partials, N);
  k_scanB<<<dim3(1), dim3(256), 0, stream>>>(partials, rowp, NB, N);
  k_scatter<<<dim3((E + 255) / 256), dim3(256), 0, stream>>>(
      srcI, dstI, eattr, rowp, partials, rank, sortedSE, E);
  k_attn<<<dim3((N + 3) / 4), dim3(256), 0, stream>>>(
      x24, x3v, p5, pb, sortedSE, rowp, partials, node_acc, N);
  k_pool<<<dim3(out_size / D, 32), dim3(D), 0, stream>>>(node_acc, batch, sums, N);
  k_final<<<dim3((out_size + 255) / 256), dim3(256), 0, stream>>>(
      sums, batch, out, N, out_size);
}